// Round 1
// baseline (34610.437 us; speedup 1.0000x reference)
//
#include <hip/hip_runtime.h>
#include <hip/hip_cooperative_groups.h>
#include <math.h>

namespace cg = cooperative_groups;

// Problem constants (fixed by the reference)
#define B_ 32
#define S_ 400
#define L_ 50
#define E_ 256
#define H_ 512
#define A_ 64
#define V_ 50000
#define VPAD 50048   // V padded to multiple of 64 for the GEMM
#define G3 1536      // 3*H

typedef unsigned short u16;
typedef __bf16 bf16x8_t __attribute__((ext_vector_type(8)));
typedef float f32x4_t __attribute__((ext_vector_type(4)));

__device__ inline u16 f2bf(float f){
  union { float f; unsigned u; } x; x.f = f;
  unsigned r = x.u + 0x7fff + ((x.u >> 16) & 1);
  return (u16)(r >> 16);
}
__device__ inline float bf2f(u16 h){
  union { unsigned u; float f; } x; x.u = ((unsigned)h) << 16;
  return x.f;
}
__device__ inline float fsig(float x){ return 1.f / (1.f + __expf(-x)); }
__device__ inline float ftanh(float x){
  float cx = fminf(15.f, fmaxf(-15.f, x));
  float e = __expf(2.f * cx);
  return (e - 1.f) * __builtin_amdgcn_rcpf(e + 1.f);
}

// ---------------------------------------------------------------------------
// Split-bf16 GEMM (~fp32 precision): C(M,N) = A(M,K) @ B(N,K)^T, f32 out.
// A ~ Ah+Al, B ~ Bh+Bl (bf16 hi/lo). acc += Ah*Bh + Al*Bh + Ah*Bl.
// 64x64 tile, BK=32, 256 threads (4 waves), wave w -> rows [w*16, w*16+16).
// M%64==0, N%64==0, K%32==0 required. Store guarded by col<nstore.
// ---------------------------------------------------------------------------
#define LDSL 56  // halfword stride (112B rows: 16B aligned, 2-way-bank-max)

__global__ __launch_bounds__(256) void k_gemm3(const u16* __restrict__ Ah,
    const u16* __restrict__ Al, const u16* __restrict__ Bh, const u16* __restrict__ Bl,
    float* __restrict__ C, int M, int N, int K, int ldc, int nstore)
{
  __shared__ u16 Ahs[64 * LDSL];
  __shared__ u16 Als[64 * LDSL];
  __shared__ u16 Bhs[64 * LDSL];
  __shared__ u16 Bls[64 * LDSL];
  const int m0 = blockIdx.y * 64, n0 = blockIdx.x * 64;
  const int tid = threadIdx.x;
  const int w = tid >> 6, l = tid & 63, q = l >> 4, r = l & 15;
  const int srow = tid >> 2, skc = (tid & 3) * 8;

  f32x4_t acc0 = {0.f,0.f,0.f,0.f};
  f32x4_t acc1 = {0.f,0.f,0.f,0.f};
  f32x4_t acc2 = {0.f,0.f,0.f,0.f};
  f32x4_t acc3 = {0.f,0.f,0.f,0.f};

  const u16* pah = Ah + (size_t)(m0 + srow) * K + skc;
  const u16* pal = Al + (size_t)(m0 + srow) * K + skc;
  const u16* pbh = Bh + (size_t)(n0 + srow) * K + skc;
  const u16* pbl = Bl + (size_t)(n0 + srow) * K + skc;

  for (int k0 = 0; k0 < K; k0 += 32, pah += 32, pal += 32, pbh += 32, pbl += 32) {
    uint4 ahv = *(const uint4*)pah;
    uint4 alv = *(const uint4*)pal;
    uint4 bhv = *(const uint4*)pbh;
    uint4 blv = *(const uint4*)pbl;
    __syncthreads();
    *(uint4*)&Ahs[srow * LDSL + skc] = ahv;
    *(uint4*)&Als[srow * LDSL + skc] = alv;
    *(uint4*)&Bhs[srow * LDSL + skc] = bhv;
    *(uint4*)&Bls[srow * LDSL + skc] = blv;
    __syncthreads();
    bf16x8_t ah = *(const bf16x8_t*)&Ahs[(w * 16 + r) * LDSL + q * 8];
    bf16x8_t al = *(const bf16x8_t*)&Als[(w * 16 + r) * LDSL + q * 8];
    bf16x8_t bh0 = *(const bf16x8_t*)&Bhs[( 0 + r) * LDSL + q * 8];
    bf16x8_t bh1 = *(const bf16x8_t*)&Bhs[(16 + r) * LDSL + q * 8];
    bf16x8_t bh2 = *(const bf16x8_t*)&Bhs[(32 + r) * LDSL + q * 8];
    bf16x8_t bh3 = *(const bf16x8_t*)&Bhs[(48 + r) * LDSL + q * 8];
    bf16x8_t bl0 = *(const bf16x8_t*)&Bls[( 0 + r) * LDSL + q * 8];
    bf16x8_t bl1 = *(const bf16x8_t*)&Bls[(16 + r) * LDSL + q * 8];
    bf16x8_t bl2 = *(const bf16x8_t*)&Bls[(32 + r) * LDSL + q * 8];
    bf16x8_t bl3 = *(const bf16x8_t*)&Bls[(48 + r) * LDSL + q * 8];
    acc0 = __builtin_amdgcn_mfma_f32_16x16x32_bf16(ah, bh0, acc0, 0, 0, 0);
    acc1 = __builtin_amdgcn_mfma_f32_16x16x32_bf16(ah, bh1, acc1, 0, 0, 0);
    acc2 = __builtin_amdgcn_mfma_f32_16x16x32_bf16(ah, bh2, acc2, 0, 0, 0);
    acc3 = __builtin_amdgcn_mfma_f32_16x16x32_bf16(ah, bh3, acc3, 0, 0, 0);
    acc0 = __builtin_amdgcn_mfma_f32_16x16x32_bf16(al, bh0, acc0, 0, 0, 0);
    acc1 = __builtin_amdgcn_mfma_f32_16x16x32_bf16(al, bh1, acc1, 0, 0, 0);
    acc2 = __builtin_amdgcn_mfma_f32_16x16x32_bf16(al, bh2, acc2, 0, 0, 0);
    acc3 = __builtin_amdgcn_mfma_f32_16x16x32_bf16(al, bh3, acc3, 0, 0, 0);
    acc0 = __builtin_amdgcn_mfma_f32_16x16x32_bf16(ah, bl0, acc0, 0, 0, 0);
    acc1 = __builtin_amdgcn_mfma_f32_16x16x32_bf16(ah, bl1, acc1, 0, 0, 0);
    acc2 = __builtin_amdgcn_mfma_f32_16x16x32_bf16(ah, bl2, acc2, 0, 0, 0);
    acc3 = __builtin_amdgcn_mfma_f32_16x16x32_bf16(ah, bl3, acc3, 0, 0, 0);
  }

  f32x4_t accs[4] = {acc0, acc1, acc2, acc3};
  #pragma unroll
  for (int nt = 0; nt < 4; nt++) {
    #pragma unroll
    for (int i = 0; i < 4; i++) {
      int row = m0 + w * 16 + q * 4 + i;
      int col = n0 + nt * 16 + r;
      if (col < nstore)
        C[(size_t)row * ldc + col] = accs[nt][i];
    }
  }
}

// ---------------------------------------------------------------------------
// Setup / conversion kernels
// ---------------------------------------------------------------------------

// f32 -> bf16 hi/lo split convert with optional zero-padded rows.
__global__ __launch_bounds__(256) void k_conv(const float* __restrict__ src,
    u16* __restrict__ dh, u16* __restrict__ dl, int rows, int cols, int ld, long total)
{
  long gid = (long)blockIdx.x * 256 + threadIdx.x;
  if (gid >= total) return;
  int r = (int)(gid / cols), c = (int)(gid % cols);
  float v = (r < rows) ? src[(size_t)r * ld + c] : 0.f;
  u16 hi = f2bf(v);
  dh[gid] = hi;
  dl[gid] = f2bf(v - bf2f(hi));
}

// x_sbe[(s*32+b)][e] = split(embed_W[src[b][s]][e])
__global__ __launch_bounds__(256) void k_embed(const int* __restrict__ src,
    const float* __restrict__ embW, u16* __restrict__ xh, u16* __restrict__ xl)
{
  int sb = blockIdx.x;            // s*32+b
  int s = sb >> 5, b = sb & 31;
  int id = src[b * S_ + s];
  float v = embW[(size_t)id * E_ + threadIdx.x];
  u16 hi = f2bf(v);
  xh[(size_t)sb * E_ + threadIdx.x] = hi;
  xl[(size_t)sb * E_ + threadIdx.x] = f2bf(v - bf2f(hi));
}

// pe[(l*32+b)][e] = split(embed_W[l==0 ? 1 : trg[b][l-1]][e])
__global__ __launch_bounds__(256) void k_pe(const int* __restrict__ trg,
    const float* __restrict__ embW, u16* __restrict__ ph, u16* __restrict__ pl)
{
  int lb = blockIdx.x;            // l*32+b
  int l = lb >> 5, b = lb & 31;
  int id = (l == 0) ? 1 : trg[b * L_ + (l - 1)];
  float v = embW[(size_t)id * E_ + threadIdx.x];
  u16 hi = f2bf(v);
  ph[(size_t)lb * E_ + threadIdx.x] = hi;
  pl[(size_t)lb * E_ + threadIdx.x] = f2bf(v - bf2f(hi));
}

// up_biasT[gr][b] = dec_bih[gr] + u[b].Wu_row + p[b].Wp_row
__global__ __launch_bounds__(256) void k_upbias(const int* __restrict__ user,
    const int* __restrict__ product, const float* __restrict__ userW,
    const float* __restrict__ prodW, const float* __restrict__ decWih,
    const float* __restrict__ bih, float* __restrict__ upbT)
{
  int gid = blockIdx.x * 256 + threadIdx.x;  // gr*32+b, 49152 total
  int gr = gid >> 5, b = gid & 31;
  const float* uu = userW + (size_t)user[b] * A_;
  const float* pp = prodW + (size_t)product[b] * A_;
  const float* wrow = decWih + (size_t)gr * (E_ + H_ + 2 * A_);
  float a = bih[gr];
  #pragma unroll 4
  for (int k = 0; k < A_; k++) a = fmaf(uu[k], wrow[E_ + H_ + k], a);
  #pragma unroll 4
  for (int k = 0; k < A_; k++) a = fmaf(pp[k], wrow[E_ + H_ + A_ + k], a);
  upbT[gid] = a;
}

// ehid[(b*400+s)][0:512]=hs_f[s][b][:], [512:1024]=hs_b[s][b][:]  (hi/lo split)
__global__ __launch_bounds__(256) void k_pack(const float* __restrict__ hs_f,
    const float* __restrict__ hs_b, u16* __restrict__ eh, u16* __restrict__ el)
{
  int bs = blockIdx.x;            // b*400+s
  int b = bs / S_, s = bs % S_;
  int d = threadIdx.x;
  #pragma unroll
  for (int i = 0; i < 4; i++) {
    int dd = d + i * 256;
    float v = (dd < H_) ? hs_f[(size_t)s * (B_ * H_) + b * H_ + dd]
                        : hs_b[(size_t)s * (B_ * H_) + b * H_ + (dd - H_)];
    u16 hi = f2bf(v);
    eh[(size_t)bs * (2 * H_) + dd] = hi;
    el[(size_t)bs * (2 * H_) + dd] = f2bf(v - bf2f(hi));
  }
}

// ---------------------------------------------------------------------------
// Persistent encoder: both directions, all 400 steps, one cooperative launch.
// grid = 128 blocks (dir x 64 jc), block 256 = (32 b x 8 u).
// Whh rows for this block's 8 j live in LDS (48 KB), loaded once.
// h stored transposed in global ping-pong: hP[dir][k][b]. One grid sync/step.
// ---------------------------------------------------------------------------
__global__ __launch_bounds__(256) void k_enc_all(
    const float* __restrict__ gi_f, const float* __restrict__ gi_b,
    const float* __restrict__ WhhF, const float* __restrict__ WhhB,
    const float* __restrict__ bihF, const float* __restrict__ bhhF,
    const float* __restrict__ bihB, const float* __restrict__ bhhB,
    float* __restrict__ hP0, float* __restrict__ hP1,
    float* __restrict__ hs_f, float* __restrict__ hs_b)
{
  cg::grid_group grid = cg::this_grid();
  const int dir = blockIdx.x >> 6;
  const int jc  = blockIdx.x & 63;
  const int b = threadIdx.x & 31, u = threadIdx.x >> 5;
  const int j = jc * 8 + u;
  const float* gi  = dir ? gi_b  : gi_f;
  const float* Whh = dir ? WhhB : WhhF;
  const float* bih = dir ? bihB : bihF;
  const float* bhh = dir ? bhhB : bhhF;
  float* hs = dir ? hs_b : hs_f;

  __shared__ float wS[24][H_];   // [gate*8+u][k], 48 KB
  for (int idx = threadIdx.x; idx < 24 * H_; idx += 256) {
    int row = idx >> 9, k = idx & (H_ - 1);
    int g = row >> 3, uu = row & 7;
    wS[row][k] = Whh[((size_t)(g * H_ + jc * 8 + uu)) * H_ + k];
  }
  __syncthreads();

  const float b_r  = bih[j] + bhh[j];
  const float b_z  = bih[H_ + j] + bhh[H_ + j];
  const float b_in = bih[2 * H_ + j];
  const float b_hn = bhh[2 * H_ + j];
  const float* gir = gi + (size_t)j * (S_ * B_);
  const float* giz = gi + (size_t)(H_ + j) * (S_ * B_);
  const float* gin = gi + (size_t)(2 * H_ + j) * (S_ * B_);
  const float* wr = wS[u];
  const float* wz = wS[8 + u];
  const float* wn = wS[16 + u];

  for (int t = 0; t < S_; t++) {
    const float* hT = ((t & 1) ? hP1 : hP0) + dir * (H_ * B_);
    float*       hO = ((t & 1) ? hP0 : hP1) + dir * (H_ * B_);
    float ar = 0.f, az = 0.f, an = 0.f;
    #pragma unroll 2
    for (int k = 0; k < H_; k += 4) {
      float4 w4r = *(const float4*)&wr[k];
      float4 w4z = *(const float4*)&wz[k];
      float4 w4n = *(const float4*)&wn[k];
      float h0 = hT[(k + 0) * B_ + b];
      float h1 = hT[(k + 1) * B_ + b];
      float h2 = hT[(k + 2) * B_ + b];
      float h3 = hT[(k + 3) * B_ + b];
      ar = fmaf(w4r.x, h0, ar); az = fmaf(w4z.x, h0, az); an = fmaf(w4n.x, h0, an);
      ar = fmaf(w4r.y, h1, ar); az = fmaf(w4z.y, h1, az); an = fmaf(w4n.y, h1, an);
      ar = fmaf(w4r.z, h2, ar); az = fmaf(w4z.z, h2, az); an = fmaf(w4n.z, h2, an);
      ar = fmaf(w4r.w, h3, ar); az = fmaf(w4z.w, h3, az); an = fmaf(w4n.w, h3, an);
    }
    int tt = dir ? (S_ - 1 - t) : t;
    size_t col = (size_t)tt * B_ + b;
    float r = fsig(gir[col] + b_r + ar);
    float z = fsig(giz[col] + b_z + az);
    float n = ftanh(gin[col] + b_in + r * (an + b_hn));
    float hp = hT[j * B_ + b];
    float hn = (1.f - z) * n + z * hp;
    hO[j * B_ + b] = hn;
    hs[(size_t)tt * (B_ * H_) + b * H_ + j] = hn;
    grid.sync();
  }
}

// ---------------------------------------------------------------------------
// Decoder init: hidden = tanh([hf_last, hb_last] @ init_W.T + init_b)
// grid 64, block 256 = (32 b x 8 u). Writes hT0 and chT0 (both (512,32)).
// ---------------------------------------------------------------------------
__global__ __launch_bounds__(256) void k_dec_init(const float* __restrict__ hs_f,
    const float* __restrict__ hs_b, const float* __restrict__ initW,
    const float* __restrict__ initb, float* __restrict__ hT0, float* __restrict__ chT0)
{
  int b = threadIdx.x & 31, u = threadIdx.x >> 5;
  int j = blockIdx.x * 8 + u;
  const float* w = initW + (size_t)j * (2 * H_);
  float a = initb[j];
  #pragma unroll 4
  for (int k = 0; k < H_; k++)
    a = fmaf(w[k], hs_f[(size_t)(S_ - 1) * (B_ * H_) + b * H_ + k], a);
  #pragma unroll 4
  for (int k = 0; k < H_; k++)
    a = fmaf(w[H_ + k], hs_b[(size_t)b * H_ + k], a);
  float h = ftanh(a);
  hT0[j * B_ + b] = h;
  chT0[j * B_ + b] = h;
}

// ---------------------------------------------------------------------------
// Persistent decoder: all 50 steps, 6 phases per step, one cooperative launch.
// grid = 256 blocks x 256 threads; phases are block-role-guarded and separated
// by grid.sync(). Phase bodies are verbatim the previous standalone kernels.
// ---------------------------------------------------------------------------
__global__ __launch_bounds__(256) void k_dec_all(
    const float* __restrict__ gi_pe, const float* __restrict__ upbT,
    const float* __restrict__ Wih, const float* __restrict__ Whh,
    const float* __restrict__ bhh, const float* __restrict__ queryW,
    const float* __restrict__ pk, const float* __restrict__ energy,
    const int* __restrict__ mask,
    const float* __restrict__ hs_f, const float* __restrict__ hs_b,
    const float* __restrict__ chW, const float* __restrict__ genpW,
    const float* __restrict__ genpB, const u16* __restrict__ pe_hi,
    const u16* __restrict__ pe_lo,
    float* __restrict__ hD0, float* __restrict__ hD1,
    float* __restrict__ cD0, float* __restrict__ cD1,
    float* __restrict__ qWb, float* __restrict__ scores,
    float* __restrict__ alphas, float* __restrict__ ctxT,
    u16* __restrict__ ch_hi, u16* __restrict__ ch_lo,
    float* __restrict__ gp_all)
{
  cg::grid_group grid = cg::this_grid();
  const int blk = blockIdx.x;
  const int tid = threadIdx.x;
  __shared__ float sred[256];

  for (int t = 0; t < L_; t++) {
    const float* hin  = (t & 1) ? hD1 : hD0;
    float*       hout = (t & 1) ? hD0 : hD1;
    const float* cin  = (t & 1) ? cD1 : cD0;
    float*       cout = (t & 1) ? cD0 : cD1;

    // ---- phase 1: decoder GRU (blocks 0..63) ----
    if (blk < 64) {
      int b = tid & 31, u = tid >> 5;
      int j = blk * 8 + u;
      const int WI = E_ + H_ + 2 * A_;  // 896
      const float* wi_r = Wih + (size_t)j * WI + E_;
      const float* wi_z = Wih + (size_t)(H_ + j) * WI + E_;
      const float* wi_n = Wih + (size_t)(2 * H_ + j) * WI + E_;
      const float* wh_r = Whh + (size_t)j * H_;
      const float* wh_z = Whh + (size_t)(H_ + j) * H_;
      const float* wh_n = Whh + (size_t)(2 * H_ + j) * H_;
      float air = 0.f, aiz = 0.f, ain = 0.f, ahr = 0.f, ahz = 0.f, ahn = 0.f;
      #pragma unroll 2
      for (int k = 0; k < H_; k++) {
        float ck = cin[k * B_ + b];
        float hk = hin[k * B_ + b];
        air = fmaf(wi_r[k], ck, air);
        aiz = fmaf(wi_z[k], ck, aiz);
        ain = fmaf(wi_n[k], ck, ain);
        ahr = fmaf(wh_r[k], hk, ahr);
        ahz = fmaf(wh_z[k], hk, ahz);
        ahn = fmaf(wh_n[k], hk, ahn);
      }
      int col = t * B_ + b;
      float ir  = gi_pe[(size_t)j * (L_ * B_) + col]            + upbT[j * B_ + b]            + air;
      float iz  = gi_pe[(size_t)(H_ + j) * (L_ * B_) + col]     + upbT[(H_ + j) * B_ + b]     + aiz;
      float in_ = gi_pe[(size_t)(2 * H_ + j) * (L_ * B_) + col] + upbT[(2 * H_ + j) * B_ + b] + ain;
      float r = fsig(ir + ahr + bhh[j]);
      float z = fsig(iz + ahz + bhh[H_ + j]);
      float n = ftanh(in_ + r * (ahn + bhh[2 * H_ + j]));
      float hp = hin[j * B_ + b];
      hout[j * B_ + b] = (1.f - z) * n + z * hp;
    }
    grid.sync();

    // ---- phase 2: qW[b][i] = h . query_W[i] (blocks 0..63) ----
    if (blk < 64) {
      int b = tid & 31, u = tid >> 5;
      int i = blk * 8 + u;
      const float* w = queryW + (size_t)i * H_;
      float a = 0.f;
      #pragma unroll 4
      for (int k = 0; k < H_; k++) a = fmaf(w[k], hout[k * B_ + b], a);
      qWb[b * H_ + i] = a;
    }
    grid.sync();

    // ---- phase 3: scores (all 256 blocks; b = blk&31, sc = blk>>5) ----
    {
      int b = blk & 31, sc = blk >> 5;
      int wv = tid >> 6, ln = tid & 63;
      const float4* q4 = (const float4*)(qWb + b * H_) + ln * 2;
      float4 q0 = q4[0], q1 = q4[1];
      const float4* e4 = (const float4*)energy + ln * 2;
      float4 e0 = e4[0], e1 = e4[1];
      for (int i = 0; i < 13; i++) {
        int so = wv * 13 + i;
        if (so >= 50) break;
        int s = sc * 50 + so;
        const float4* p4 = (const float4*)(pk + ((size_t)b * S_ + s) * H_) + ln * 2;
        float4 p0 = p4[0], p1 = p4[1];
        float acc = 0.f;
        acc = fmaf(e0.x, ftanh(q0.x + p0.x), acc);
        acc = fmaf(e0.y, ftanh(q0.y + p0.y), acc);
        acc = fmaf(e0.z, ftanh(q0.z + p0.z), acc);
        acc = fmaf(e0.w, ftanh(q0.w + p0.w), acc);
        acc = fmaf(e1.x, ftanh(q1.x + p1.x), acc);
        acc = fmaf(e1.y, ftanh(q1.y + p1.y), acc);
        acc = fmaf(e1.z, ftanh(q1.z + p1.z), acc);
        acc = fmaf(e1.w, ftanh(q1.w + p1.w), acc);
        #pragma unroll
        for (int off = 32; off > 0; off >>= 1) acc += __shfl_xor(acc, off, 64);
        if (ln == 0)
          scores[b * S_ + s] = (mask[b * S_ + s] == 0) ? -__builtin_inff() : acc;
      }
    }
    grid.sync();

    // ---- phase 4: softmax over S=400 per batch (blocks 0..31) ----
    if (blk < 32) {
      int b = blk;
      const float* sr = scores + b * S_;
      float x1 = sr[tid];
      float x2 = (tid < S_ - 256) ? sr[256 + tid] : -__builtin_inff();
      float m = fmaxf(x1, x2);
      #pragma unroll
      for (int off = 32; off > 0; off >>= 1) m = fmaxf(m, __shfl_xor(m, off, 64));
      if ((tid & 63) == 0) sred[tid >> 6] = m;
      __syncthreads();
      m = fmaxf(fmaxf(sred[0], sred[1]), fmaxf(sred[2], sred[3]));
      __syncthreads();
      float ex1 = __expf(x1 - m);
      float ex2 = (tid < S_ - 256) ? __expf(x2 - m) : 0.f;
      float s = ex1 + ex2;
      #pragma unroll
      for (int off = 32; off > 0; off >>= 1) s += __shfl_xor(s, off, 64);
      if ((tid & 63) == 0) sred[tid >> 6] = s;
      __syncthreads();
      s = sred[0] + sred[1] + sred[2] + sred[3];
      float inv = 1.f / s;
      float* al = alphas + ((size_t)b * L_ + t) * S_;
      al[tid] = ex1 * inv;
      if (tid < S_ - 256) al[256 + tid] = ex2 * inv;
    }
    grid.sync();

    // ---- phase 5: context ctxT[d][b] (blocks 0..127; 256 d per block) ----
    if (blk < 128) {
      int b = blk & 31, dc = blk >> 5;
      int d = dc * 256 + tid;
      const float* al = alphas + ((size_t)b * L_ + t) * S_;
      const float* srcp = (d < H_) ? (hs_f + (size_t)b * H_ + d)
                                   : (hs_b + (size_t)b * H_ + (d - H_));
      float acc = 0.f;
      #pragma unroll 4
      for (int s = 0; s < S_; s++)
        acc = fmaf(al[s], srcp[(size_t)s * (B_ * H_)], acc);
      ctxT[d * B_ + b] = acc;
    }
    grid.sync();

    // ---- phase 6: ch = tanh([q, ctx] @ ch_W.T) (blocks 0..63) + gp (block 64) ----
    if (blk < 64) {
      int b = tid & 31, u = tid >> 5;
      int i = blk * 8 + u;
      const float* w = chW + (size_t)i * (3 * H_);
      float a = 0.f;
      #pragma unroll 4
      for (int k = 0; k < H_; k++)       a = fmaf(w[k],        hout[k * B_ + b], a);
      #pragma unroll 4
      for (int k = 0; k < 2 * H_; k++)   a = fmaf(w[H_ + k],   ctxT[k * B_ + b], a);
      float c = ftanh(a);
      cout[i * B_ + b] = c;
      u16 hi = f2bf(c);
      ch_hi[((size_t)b * L_ + t) * H_ + i] = hi;
      ch_lo[((size_t)b * L_ + t) * H_ + i] = f2bf(c - bf2f(hi));
    } else if (blk == 64) {
      // gp = sigmoid([context(1024), q(512), pe(256)] . genp_W + genp_b)
      int b = tid & 31, seg = tid >> 5;
      float a = 0.f;
      for (int ii = 0; ii < 224; ii++) {
        int idx = seg * 224 + ii;
        float v;
        if (idx < 2 * H_)            v = ctxT[idx * B_ + b];
        else if (idx < 3 * H_)       v = hout[(idx - 2 * H_) * B_ + b];
        else {
          size_t pidx = ((size_t)t * B_ + b) * E_ + (idx - 3 * H_);
          v = bf2f(pe_hi[pidx]) + bf2f(pe_lo[pidx]);
        }
        a = fmaf(genpW[idx], v, a);
      }
      sred[tid] = a;
      __syncthreads();
      if (tid < 32) {
        float s = 0.f;
        #pragma unroll
        for (int sg = 0; sg < 8; sg++) s += sred[sg * 32 + tid];
        gp_all[tid * L_ + t] = fsig(s + genpB[0]);
      }
    }
    grid.sync();
  }
}

// per-row (1600 rows) max & sumexp over V=50000 logits (in d_out)
__global__ __launch_bounds__(256) void k_rowstats(const float* __restrict__ logits,
    float* __restrict__ stats)
{
  int row = blockIdx.x;
  int tid = threadIdx.x;
  __shared__ float red[8];
  const float* p = logits + (size_t)row * V_;
  float m = -__builtin_inff();
  for (int c = tid; c < V_; c += 256) m = fmaxf(m, p[c]);
  #pragma unroll
  for (int off = 32; off > 0; off >>= 1) m = fmaxf(m, __shfl_xor(m, off, 64));
  if ((tid & 63) == 0) red[tid >> 6] = m;
  __syncthreads();
  m = fmaxf(fmaxf(red[0], red[1]), fmaxf(red[2], red[3]));
  __syncthreads();
  float s = 0.f;
  for (int c = tid; c < V_; c += 256) s += __expf(p[c] - m);
  #pragma unroll
  for (int off = 32; off > 0; off >>= 1) s += __shfl_xor(s, off, 64);
  if ((tid & 63) == 0) red[tid >> 6] = s;
  __syncthreads();
  if (tid == 0) {
    stats[row * 2]     = m;
    stats[row * 2 + 1] = red[0] + red[1] + red[2] + red[3];
  }
}

// out = gp * softmax(logits) in-place; grid (49, 1600), float4 per thread
__global__ __launch_bounds__(256) void k_mix(float* __restrict__ out,
    const float* __restrict__ stats, const float* __restrict__ gp_all)
{
  int row = blockIdx.y;
  int c4 = blockIdx.x * 256 + threadIdx.x;
  if (c4 >= V_ / 4) return;
  float m = stats[row * 2], s = stats[row * 2 + 1];
  float inv = gp_all[row] / s;
  float4* p = (float4*)(out + (size_t)row * V_) + c4;
  float4 v = *p;
  v.x = __expf(v.x - m) * inv;
  v.y = __expf(v.y - m) * inv;
  v.z = __expf(v.z - m) * inv;
  v.w = __expf(v.w - m) * inv;
  *p = v;
}

// copy mechanism: out[b,l,src[b,s]] += (1-gp)*alpha
__global__ __launch_bounds__(256) void k_scatter(float* __restrict__ out,
    const float* __restrict__ alphas, const float* __restrict__ gp_all,
    const int* __restrict__ src)
{
  int gid = blockIdx.x * 256 + threadIdx.x;
  if (gid >= B_ * L_ * S_) return;
  int s = gid % S_;
  int bl = gid / S_;     // b*50+l
  int b = bl / L_;
  float a = alphas[(size_t)bl * S_ + s];
  float g = gp_all[bl];
  int v = src[b * S_ + s];
  atomicAdd(out + (size_t)bl * V_ + v, (1.f - g) * a);
}

// ---------------------------------------------------------------------------
// Host launcher
// ---------------------------------------------------------------------------
extern "C" void kernel_launch(void* const* d_in, const int* in_sizes, int n_in,
                              void* d_out, int out_size, void* d_ws, size_t ws_size,
                              hipStream_t stream) {
  const int*   src     = (const int*)d_in[0];
  const int*   trg     = (const int*)d_in[1];
  const int*   user    = (const int*)d_in[2];
  const int*   product = (const int*)d_in[3];
  const int*   mask    = (const int*)d_in[4];
  const float* embW    = (const float*)d_in[6];
  const float* userW   = (const float*)d_in[7];
  const float* prodW   = (const float*)d_in[8];
  const float* eWihF   = (const float*)d_in[9];
  const float* eWhhF   = (const float*)d_in[10];
  const float* eBihF   = (const float*)d_in[11];
  const float* eBhhF   = (const float*)d_in[12];
  const float* eWihB   = (const float*)d_in[13];
  const float* eWhhB   = (const float*)d_in[14];
  const float* eBihB   = (const float*)d_in[15];
  const float* eBhhB   = (const float*)d_in[16];
  const float* initW   = (const float*)d_in[17];
  const float* initB   = (const float*)d_in[18];
  const float* keyW    = (const float*)d_in[19];
  const float* queryW  = (const float*)d_in[20];
  const float* energyW = (const float*)d_in[21];
  const float* decWih  = (const float*)d_in[22];
  const float* decWhh  = (const float*)d_in[23];
  const float* decBih  = (const float*)d_in[24];
  const float* decBhh  = (const float*)d_in[25];
  const float* chW     = (const float*)d_in[26];
  const float* genpW   = (const float*)d_in[27];
  const float* genpB   = (const float*)d_in[28];
  const float* genW    = (const float*)d_in[29];
  float* out = (float*)d_out;

  char* ws = (char*)d_ws;
  size_t off = 0;
  auto alloc = [&](size_t bytes) -> void* {
    void* p = ws + off;
    off = (off + bytes + 255) & ~(size_t)255;
    return p;
  };

  // Persistent buffers
  u16* x_hi    = (u16*)alloc((size_t)S_ * B_ * E_ * 2);
  u16* x_lo    = (u16*)alloc((size_t)S_ * B_ * E_ * 2);
  u16* wihF_hi = (u16*)alloc((size_t)G3 * E_ * 2);
  u16* wihF_lo = (u16*)alloc((size_t)G3 * E_ * 2);
  u16* wihB_hi = (u16*)alloc((size_t)G3 * E_ * 2);
  u16* wihB_lo = (u16*)alloc((size_t)G3 * E_ * 2);
  u16* wpe_hi  = (u16*)alloc((size_t)G3 * E_ * 2);
  u16* wpe_lo  = (u16*)alloc((size_t)G3 * E_ * 2);
  u16* key_hi  = (u16*)alloc((size_t)H_ * 2 * H_ * 2);
  u16* key_lo  = (u16*)alloc((size_t)H_ * 2 * H_ * 2);
  u16* pe_hi   = (u16*)alloc((size_t)L_ * B_ * E_ * 2);
  u16* pe_lo   = (u16*)alloc((size_t)L_ * B_ * E_ * 2);
  float* gi_pe = (float*)alloc((size_t)G3 * L_ * B_ * 4);
  float* hs_f  = (float*)alloc((size_t)S_ * B_ * H_ * 4);
  float* hs_b  = (float*)alloc((size_t)S_ * B_ * H_ * 4);
  float* hTe0  = (float*)alloc(2 * H_ * B_ * 4);
  float* hTe1  = (float*)alloc(2 * H_ * B_ * 4);
  float* upbT  = (float*)alloc((size_t)G3 * B_ * 4);
  float* hD0   = (float*)alloc(H_ * B_ * 4);
  float* hD1   = (float*)alloc(H_ * B_ * 4);
  float* cD0   = (float*)alloc(H_ * B_ * 4);
  float* cD1   = (float*)alloc(H_ * B_ * 4);
  float* qW    = (float*)alloc(B_ * H_ * 4);
  float* scores= (float*)alloc(B_ * S_ * 4);
  float* ctxT  = (float*)alloc(2 * H_ * B_ * 4);
  float* alphas= (float*)alloc((size_t)B_ * L_ * S_ * 4);
  float* gp_all= (float*)alloc(B_ * L_ * 4);
  u16* ch_hi   = (u16*)alloc((size_t)B_ * L_ * H_ * 2);
  u16* ch_lo   = (u16*)alloc((size_t)B_ * L_ * H_ * 2);
  float* stats = (float*)alloc(B_ * L_ * 2 * 4);

  // Aliased region: phase1 {gi_f, gi_b fp32} -> phase2 {genW hi/lo, ehid hi/lo, pk}
  size_t ph1 = 2 * (size_t)G3 * S_ * B_ * 4;                               // 157.3 MB
  size_t ph2 = 2 * (size_t)VPAD * H_ * 2 + 2 * (size_t)B_ * S_ * 2 * H_ * 2
             + (size_t)B_ * S_ * H_ * 4;                                   // 181.1 MB
  char* region = (char*)alloc(ph1 > ph2 ? ph1 : ph2);
  float* gi_f = (float*)region;
  float* gi_b = gi_f + (size_t)G3 * S_ * B_;
  u16* genw_hi = (u16*)region;
  u16* genw_lo = genw_hi + (size_t)VPAD * H_;
  u16* ehid_hi = genw_lo + (size_t)VPAD * H_;
  u16* ehid_lo = ehid_hi + (size_t)B_ * S_ * 2 * H_;
  float* pk    = (float*)(ehid_lo + (size_t)B_ * S_ * 2 * H_);
  (void)ws_size; (void)in_sizes; (void)n_in; (void)out_size;

  // ---- setup / conversions ----
  hipMemsetAsync(hTe0, 0, 2 * H_ * B_ * 4, stream);

  k_embed<<<S_ * B_, 256, 0, stream>>>(src, embW, x_hi, x_lo);
  k_pe<<<L_ * B_, 256, 0, stream>>>(trg, embW, pe_hi, pe_lo);

  {
    long tot = (long)G3 * E_;
    k_conv<<<(tot + 255) / 256, 256, 0, stream>>>(eWihF, wihF_hi, wihF_lo, G3, E_, E_, tot);
    k_conv<<<(tot + 255) / 256, 256, 0, stream>>>(eWihB, wihB_hi, wihB_lo, G3, E_, E_, tot);
    k_conv<<<(tot + 255) / 256, 256, 0, stream>>>(decWih, wpe_hi, wpe_lo, G3, E_, E_ + H_ + 2 * A_, tot);
    long tk = (long)H_ * 2 * H_;
    k_conv<<<(tk + 255) / 256, 256, 0, stream>>>(keyW, key_hi, key_lo, H_, 2 * H_, 2 * H_, tk);
  }
  k_upbias<<<(G3 * B_) / 256, 256, 0, stream>>>(user, product, userW, prodW, decWih, decBih, upbT);

  // gi = Wih @ x^T : (1536, 12800) f32
  k_gemm3<<<dim3((S_ * B_) / 64, G3 / 64), 256, 0, stream>>>(wihF_hi, wihF_lo, x_hi, x_lo, gi_f, G3, S_ * B_, E_, S_ * B_, S_ * B_);
  k_gemm3<<<dim3((S_ * B_) / 64, G3 / 64), 256, 0, stream>>>(wihB_hi, wihB_lo, x_hi, x_lo, gi_b, G3, S_ * B_, E_, S_ * B_, S_ * B_);

  // gi_pe = Wpe @ pe^T : (1536, 1600) f32  (uses persistent buffers only)
  k_gemm3<<<dim3((L_ * B_) / 64, G3 / 64), 256, 0, stream>>>(wpe_hi, wpe_lo, pe_hi, pe_lo, gi_pe, G3, L_ * B_, E_, L_ * B_, L_ * B_);

  // ---- encoder recurrence: ONE cooperative launch (400 grid syncs) ----
  {
    void* eargs[] = {(void*)&gi_f, (void*)&gi_b, (void*)&eWhhF, (void*)&eWhhB,
                     (void*)&eBihF, (void*)&eBhhF, (void*)&eBihB, (void*)&eBhhB,
                     (void*)&hTe0, (void*)&hTe1, (void*)&hs_f, (void*)&hs_b};
    hipLaunchCooperativeKernel(k_enc_all, dim3(128), dim3(256), eargs, 0, stream);
  }

  // ---- phase 2 of aliased region: gi_f/gi_b dead from here on ----
  {
    long tg = (long)VPAD * H_;
    k_conv<<<(tg + 255) / 256, 256, 0, stream>>>(genW, genw_hi, genw_lo, V_, H_, H_, tg);
  }
  k_pack<<<B_ * S_, 256, 0, stream>>>(hs_f, hs_b, ehid_hi, ehid_lo);
  // proj_key = ehid @ key_W^T : (12800, 512) f32
  k_gemm3<<<dim3(H_ / 64, (B_ * S_) / 64), 256, 0, stream>>>(ehid_hi, ehid_lo, key_hi, key_lo, pk, B_ * S_, H_, 2 * H_, H_, H_);

  k_dec_init<<<64, 256, 0, stream>>>(hs_f, hs_b, initW, initB, hD0, cD0);

  // ---- decoder recurrence: ONE cooperative launch (50 steps x 6 phases) ----
  {
    void* dargs[] = {(void*)&gi_pe, (void*)&upbT, (void*)&decWih, (void*)&decWhh,
                     (void*)&decBhh, (void*)&queryW, (void*)&pk, (void*)&energyW,
                     (void*)&mask, (void*)&hs_f, (void*)&hs_b, (void*)&chW,
                     (void*)&genpW, (void*)&genpB, (void*)&pe_hi, (void*)&pe_lo,
                     (void*)&hD0, (void*)&hD1, (void*)&cD0, (void*)&cD1,
                     (void*)&qW, (void*)&scores, (void*)&alphas, (void*)&ctxT,
                     (void*)&ch_hi, (void*)&ch_lo, (void*)&gp_all};
    hipLaunchCooperativeKernel(k_dec_all, dim3(256), dim3(256), dargs, 0, stream);
  }

  // ---- output: gen logits -> softmax mix -> copy scatter ----
  k_gemm3<<<dim3(VPAD / 64, (B_ * L_) / 64), 256, 0, stream>>>(ch_hi, ch_lo, genw_hi, genw_lo, out, B_ * L_, VPAD, H_, V_, V_);
  k_rowstats<<<B_ * L_, 256, 0, stream>>>(out, stats);
  k_mix<<<dim3((V_ / 4 + 255) / 256, B_ * L_), 256, 0, stream>>>(out, stats, gp_all);
  k_scatter<<<(B_ * L_ * S_ + 255) / 256, 256, 0, stream>>>(out, alphas, gp_all, src);
}

// Round 2
// 13584.293 us; speedup vs baseline: 2.5478x; 2.5478x over previous
//
#include <hip/hip_runtime.h>
#include <math.h>

// Problem constants (fixed by the reference)
#define B_ 32
#define S_ 400
#define L_ 50
#define E_ 256
#define H_ 512
#define A_ 64
#define V_ 50000
#define VPAD 50048   // V padded to multiple of 64 for the GEMM
#define G3 1536      // 3*H

typedef unsigned short u16;
typedef __bf16 bf16x8_t __attribute__((ext_vector_type(8)));
typedef float f32x4_t __attribute__((ext_vector_type(4)));

__device__ inline u16 f2bf(float f){
  union { float f; unsigned u; } x; x.f = f;
  unsigned r = x.u + 0x7fff + ((x.u >> 16) & 1);
  return (u16)(r >> 16);
}
__device__ inline float bf2f(u16 h){
  union { unsigned u; float f; } x; x.u = ((unsigned)h) << 16;
  return x.f;
}
__device__ inline float fsig(float x){ return 1.f / (1.f + __expf(-x)); }
__device__ inline float ftanh(float x){
  float cx = fminf(15.f, fmaxf(-15.f, x));
  float e = __expf(2.f * cx);
  return (e - 1.f) * __builtin_amdgcn_rcpf(e + 1.f);
}

// ---------------------------------------------------------------------------
// Split-bf16 GEMM (~fp32 precision): C(M,N) = A(M,K) @ B(N,K)^T, f32 out.
// ---------------------------------------------------------------------------
#define LDSL 56  // halfword stride (112B rows: 16B aligned, 2-way-bank-max)

__global__ __launch_bounds__(256) void k_gemm3(const u16* __restrict__ Ah,
    const u16* __restrict__ Al, const u16* __restrict__ Bh, const u16* __restrict__ Bl,
    float* __restrict__ C, int M, int N, int K, int ldc, int nstore)
{
  __shared__ u16 Ahs[64 * LDSL];
  __shared__ u16 Als[64 * LDSL];
  __shared__ u16 Bhs[64 * LDSL];
  __shared__ u16 Bls[64 * LDSL];
  const int m0 = blockIdx.y * 64, n0 = blockIdx.x * 64;
  const int tid = threadIdx.x;
  const int w = tid >> 6, l = tid & 63, q = l >> 4, r = l & 15;
  const int srow = tid >> 2, skc = (tid & 3) * 8;

  f32x4_t acc0 = {0.f,0.f,0.f,0.f};
  f32x4_t acc1 = {0.f,0.f,0.f,0.f};
  f32x4_t acc2 = {0.f,0.f,0.f,0.f};
  f32x4_t acc3 = {0.f,0.f,0.f,0.f};

  const u16* pah = Ah + (size_t)(m0 + srow) * K + skc;
  const u16* pal = Al + (size_t)(m0 + srow) * K + skc;
  const u16* pbh = Bh + (size_t)(n0 + srow) * K + skc;
  const u16* pbl = Bl + (size_t)(n0 + srow) * K + skc;

  for (int k0 = 0; k0 < K; k0 += 32, pah += 32, pal += 32, pbh += 32, pbl += 32) {
    uint4 ahv = *(const uint4*)pah;
    uint4 alv = *(const uint4*)pal;
    uint4 bhv = *(const uint4*)pbh;
    uint4 blv = *(const uint4*)pbl;
    __syncthreads();
    *(uint4*)&Ahs[srow * LDSL + skc] = ahv;
    *(uint4*)&Als[srow * LDSL + skc] = alv;
    *(uint4*)&Bhs[srow * LDSL + skc] = bhv;
    *(uint4*)&Bls[srow * LDSL + skc] = blv;
    __syncthreads();
    bf16x8_t ah = *(const bf16x8_t*)&Ahs[(w * 16 + r) * LDSL + q * 8];
    bf16x8_t al = *(const bf16x8_t*)&Als[(w * 16 + r) * LDSL + q * 8];
    bf16x8_t bh0 = *(const bf16x8_t*)&Bhs[( 0 + r) * LDSL + q * 8];
    bf16x8_t bh1 = *(const bf16x8_t*)&Bhs[(16 + r) * LDSL + q * 8];
    bf16x8_t bh2 = *(const bf16x8_t*)&Bhs[(32 + r) * LDSL + q * 8];
    bf16x8_t bh3 = *(const bf16x8_t*)&Bhs[(48 + r) * LDSL + q * 8];
    bf16x8_t bl0 = *(const bf16x8_t*)&Bls[( 0 + r) * LDSL + q * 8];
    bf16x8_t bl1 = *(const bf16x8_t*)&Bls[(16 + r) * LDSL + q * 8];
    bf16x8_t bl2 = *(const bf16x8_t*)&Bls[(32 + r) * LDSL + q * 8];
    bf16x8_t bl3 = *(const bf16x8_t*)&Bls[(48 + r) * LDSL + q * 8];
    acc0 = __builtin_amdgcn_mfma_f32_16x16x32_bf16(ah, bh0, acc0, 0, 0, 0);
    acc1 = __builtin_amdgcn_mfma_f32_16x16x32_bf16(ah, bh1, acc1, 0, 0, 0);
    acc2 = __builtin_amdgcn_mfma_f32_16x16x32_bf16(ah, bh2, acc2, 0, 0, 0);
    acc3 = __builtin_amdgcn_mfma_f32_16x16x32_bf16(ah, bh3, acc3, 0, 0, 0);
    acc0 = __builtin_amdgcn_mfma_f32_16x16x32_bf16(al, bh0, acc0, 0, 0, 0);
    acc1 = __builtin_amdgcn_mfma_f32_16x16x32_bf16(al, bh1, acc1, 0, 0, 0);
    acc2 = __builtin_amdgcn_mfma_f32_16x16x32_bf16(al, bh2, acc2, 0, 0, 0);
    acc3 = __builtin_amdgcn_mfma_f32_16x16x32_bf16(al, bh3, acc3, 0, 0, 0);
    acc0 = __builtin_amdgcn_mfma_f32_16x16x32_bf16(ah, bl0, acc0, 0, 0, 0);
    acc1 = __builtin_amdgcn_mfma_f32_16x16x32_bf16(ah, bl1, acc1, 0, 0, 0);
    acc2 = __builtin_amdgcn_mfma_f32_16x16x32_bf16(ah, bl2, acc2, 0, 0, 0);
    acc3 = __builtin_amdgcn_mfma_f32_16x16x32_bf16(ah, bl3, acc3, 0, 0, 0);
  }

  f32x4_t accs[4] = {acc0, acc1, acc2, acc3};
  #pragma unroll
  for (int nt = 0; nt < 4; nt++) {
    #pragma unroll
    for (int i = 0; i < 4; i++) {
      int row = m0 + w * 16 + q * 4 + i;
      int col = n0 + nt * 16 + r;
      if (col < nstore)
        C[(size_t)row * ldc + col] = accs[nt][i];
    }
  }
}

// ---------------------------------------------------------------------------
// Setup / conversion kernels (unchanged)
// ---------------------------------------------------------------------------
__global__ __launch_bounds__(256) void k_conv(const float* __restrict__ src,
    u16* __restrict__ dh, u16* __restrict__ dl, int rows, int cols, int ld, long total)
{
  long gid = (long)blockIdx.x * 256 + threadIdx.x;
  if (gid >= total) return;
  int r = (int)(gid / cols), c = (int)(gid % cols);
  float v = (r < rows) ? src[(size_t)r * ld + c] : 0.f;
  u16 hi = f2bf(v);
  dh[gid] = hi;
  dl[gid] = f2bf(v - bf2f(hi));
}

__global__ __launch_bounds__(256) void k_embed(const int* __restrict__ src,
    const float* __restrict__ embW, u16* __restrict__ xh, u16* __restrict__ xl)
{
  int sb = blockIdx.x;            // s*32+b
  int s = sb >> 5, b = sb & 31;
  int id = src[b * S_ + s];
  float v = embW[(size_t)id * E_ + threadIdx.x];
  u16 hi = f2bf(v);
  xh[(size_t)sb * E_ + threadIdx.x] = hi;
  xl[(size_t)sb * E_ + threadIdx.x] = f2bf(v - bf2f(hi));
}

__global__ __launch_bounds__(256) void k_pe(const int* __restrict__ trg,
    const float* __restrict__ embW, u16* __restrict__ ph, u16* __restrict__ pl)
{
  int lb = blockIdx.x;            // l*32+b
  int l = lb >> 5, b = lb & 31;
  int id = (l == 0) ? 1 : trg[b * L_ + (l - 1)];
  float v = embW[(size_t)id * E_ + threadIdx.x];
  u16 hi = f2bf(v);
  ph[(size_t)lb * E_ + threadIdx.x] = hi;
  pl[(size_t)lb * E_ + threadIdx.x] = f2bf(v - bf2f(hi));
}

__global__ __launch_bounds__(256) void k_upbias(const int* __restrict__ user,
    const int* __restrict__ product, const float* __restrict__ userW,
    const float* __restrict__ prodW, const float* __restrict__ decWih,
    const float* __restrict__ bih, float* __restrict__ upbT)
{
  int gid = blockIdx.x * 256 + threadIdx.x;  // gr*32+b, 49152 total
  int gr = gid >> 5, b = gid & 31;
  const float* uu = userW + (size_t)user[b] * A_;
  const float* pp = prodW + (size_t)product[b] * A_;
  const float* wrow = decWih + (size_t)gr * (E_ + H_ + 2 * A_);
  float a = bih[gr];
  #pragma unroll 4
  for (int k = 0; k < A_; k++) a = fmaf(uu[k], wrow[E_ + H_ + k], a);
  #pragma unroll 4
  for (int k = 0; k < A_; k++) a = fmaf(pp[k], wrow[E_ + H_ + A_ + k], a);
  upbT[gid] = a;
}

__global__ __launch_bounds__(256) void k_pack(const float* __restrict__ hs_f,
    const float* __restrict__ hs_b, u16* __restrict__ eh, u16* __restrict__ el)
{
  int bs = blockIdx.x;            // b*400+s
  int b = bs / S_, s = bs % S_;
  int d = threadIdx.x;
  #pragma unroll
  for (int i = 0; i < 4; i++) {
    int dd = d + i * 256;
    float v = (dd < H_) ? hs_f[(size_t)s * (B_ * H_) + b * H_ + dd]
                        : hs_b[(size_t)s * (B_ * H_) + b * H_ + (dd - H_)];
    u16 hi = f2bf(v);
    eh[(size_t)bs * (2 * H_) + dd] = hi;
    el[(size_t)bs * (2 * H_) + dd] = f2bf(v - bf2f(hi));
  }
}

// ---------------------------------------------------------------------------
// Encoder GRU step, k-split for occupancy + float4 loads.
// grid 512: blk = dir*256 + jc (2 j per block). block 256: tid = b + 32*slot,
// slot = u*4+ks (u: which j of the pair, ks: 128-wide k-chunk).
// h state layout: hB[dir][b][k] (contiguous k). hs output unchanged (t,b,h).
// ---------------------------------------------------------------------------
__global__ __launch_bounds__(256) void k_enc_step2(
    const float* __restrict__ gi_f, const float* __restrict__ gi_b,
    const float* __restrict__ WhhF, const float* __restrict__ WhhB,
    const float* __restrict__ bihF, const float* __restrict__ bhhF,
    const float* __restrict__ bihB, const float* __restrict__ bhhB,
    const float* __restrict__ hB_in, float* __restrict__ hB_out,
    float* __restrict__ hs_f, float* __restrict__ hs_b, int t)
{
  __shared__ float red[8 * 3 * 32];
  const int dir = blockIdx.x >> 8;
  const int jc  = blockIdx.x & 255;
  const int tid = threadIdx.x;
  const int b = tid & 31, slot = tid >> 5, u = slot >> 2, ks = slot & 3;
  const int j = jc * 2 + u;
  const float* Whh = dir ? WhhB : WhhF;

  const float4* h4p = (const float4*)(hB_in + (size_t)dir * (B_ * H_) + b * H_ + ks * 128);
  const float4* wr4 = (const float4*)(Whh + (size_t)j * H_ + ks * 128);
  const float4* wz4 = (const float4*)(Whh + (size_t)(H_ + j) * H_ + ks * 128);
  const float4* wn4 = (const float4*)(Whh + (size_t)(2 * H_ + j) * H_ + ks * 128);

  float ar = 0.f, az = 0.f, an = 0.f;
  #pragma unroll 4
  for (int k4 = 0; k4 < 32; k4++) {
    float4 hv = h4p[k4];
    float4 rv = wr4[k4];
    float4 zv = wz4[k4];
    float4 nv = wn4[k4];
    ar = fmaf(rv.x, hv.x, ar); az = fmaf(zv.x, hv.x, az); an = fmaf(nv.x, hv.x, an);
    ar = fmaf(rv.y, hv.y, ar); az = fmaf(zv.y, hv.y, az); an = fmaf(nv.y, hv.y, an);
    ar = fmaf(rv.z, hv.z, ar); az = fmaf(zv.z, hv.z, az); an = fmaf(nv.z, hv.z, an);
    ar = fmaf(rv.w, hv.w, ar); az = fmaf(zv.w, hv.w, az); an = fmaf(nv.w, hv.w, an);
  }
  red[(slot * 3 + 0) * 32 + b] = ar;
  red[(slot * 3 + 1) * 32 + b] = az;
  red[(slot * 3 + 2) * 32 + b] = an;
  __syncthreads();

  if (tid < 64) {
    int bb = tid & 31, uu = tid >> 5;
    int jj = jc * 2 + uu;
    float sr = 0.f, sz = 0.f, sn = 0.f;
    #pragma unroll
    for (int s2 = uu * 4; s2 < uu * 4 + 4; s2++) {
      sr += red[(s2 * 3 + 0) * 32 + bb];
      sz += red[(s2 * 3 + 1) * 32 + bb];
      sn += red[(s2 * 3 + 2) * 32 + bb];
    }
    const float* gi  = dir ? gi_b : gi_f;
    const float* bih = dir ? bihB : bihF;
    const float* bhh = dir ? bhhB : bhhF;
    int tt = dir ? (S_ - 1 - t) : t;
    size_t col = (size_t)tt * B_ + bb;
    float gr = gi[(size_t)jj * (S_ * B_) + col]            + bih[jj]          + bhh[jj]      + sr;
    float gz = gi[(size_t)(H_ + jj) * (S_ * B_) + col]     + bih[H_ + jj]     + bhh[H_ + jj] + sz;
    float gn = gi[(size_t)(2 * H_ + jj) * (S_ * B_) + col] + bih[2 * H_ + jj];
    float r = fsig(gr);
    float z = fsig(gz);
    float n = ftanh(gn + r * (sn + bhh[2 * H_ + jj]));
    float hp = hB_in[(size_t)dir * (B_ * H_) + bb * H_ + jj];
    float hn = (1.f - z) * n + z * hp;
    hB_out[(size_t)dir * (B_ * H_) + bb * H_ + jj] = hn;
    (dir ? hs_b : hs_f)[(size_t)tt * (B_ * H_) + bb * H_ + jj] = hn;
  }
}

// ---------------------------------------------------------------------------
// Decoder init: writes hB0/cB0 in [b][j] layout.
// ---------------------------------------------------------------------------
__global__ __launch_bounds__(256) void k_dec_init(const float* __restrict__ hs_f,
    const float* __restrict__ hs_b, const float* __restrict__ initW,
    const float* __restrict__ initb, float* __restrict__ hB0, float* __restrict__ cB0)
{
  int b = threadIdx.x & 31, u = threadIdx.x >> 5;
  int j = blockIdx.x * 8 + u;
  const float* w = initW + (size_t)j * (2 * H_);
  float a = initb[j];
  #pragma unroll 4
  for (int k = 0; k < H_; k++)
    a = fmaf(w[k], hs_f[(size_t)(S_ - 1) * (B_ * H_) + b * H_ + k], a);
  #pragma unroll 4
  for (int k = 0; k < H_; k++)
    a = fmaf(w[H_ + k], hs_b[(size_t)b * H_ + k], a);
  float h = ftanh(a);
  hB0[b * H_ + j] = h;
  cB0[b * H_ + j] = h;
}

// ---------------------------------------------------------------------------
// Decoder GRU step, k-split. grid 256 (2 j each), block 256 = 32b x 2u x 4ks.
// State layouts: hB/cB = [b][k].
// ---------------------------------------------------------------------------
__global__ __launch_bounds__(256) void k_dec_gru2(
    const float* __restrict__ gi_pe, const float* __restrict__ upbT,
    const float* __restrict__ Wih, const float* __restrict__ Whh,
    const float* __restrict__ bhh,
    const float* __restrict__ hB_in, const float* __restrict__ cB_in,
    float* __restrict__ hB_out, int t)
{
  __shared__ float red[8 * 6 * 32];
  const int jc = blockIdx.x;
  const int tid = threadIdx.x;
  const int b = tid & 31, slot = tid >> 5, u = slot >> 2, ks = slot & 3;
  const int j = jc * 2 + u;
  const int WI = E_ + H_ + 2 * A_;  // 896
  const float4* wir4 = (const float4*)(Wih + (size_t)j * WI + E_ + ks * 128);
  const float4* wiz4 = (const float4*)(Wih + (size_t)(H_ + j) * WI + E_ + ks * 128);
  const float4* win4 = (const float4*)(Wih + (size_t)(2 * H_ + j) * WI + E_ + ks * 128);
  const float4* whr4 = (const float4*)(Whh + (size_t)j * H_ + ks * 128);
  const float4* whz4 = (const float4*)(Whh + (size_t)(H_ + j) * H_ + ks * 128);
  const float4* whn4 = (const float4*)(Whh + (size_t)(2 * H_ + j) * H_ + ks * 128);
  const float4* c4 = (const float4*)(cB_in + b * H_ + ks * 128);
  const float4* h4 = (const float4*)(hB_in + b * H_ + ks * 128);

  float air = 0.f, aiz = 0.f, ain = 0.f, ahr = 0.f, ahz = 0.f, ahn = 0.f;
  #pragma unroll 2
  for (int k4 = 0; k4 < 32; k4++) {
    float4 cv = c4[k4];
    float4 hv = h4[k4];
    float4 ir = wir4[k4], iz = wiz4[k4], in = win4[k4];
    float4 hr = whr4[k4], hz = whz4[k4], hn = whn4[k4];
    air = fmaf(ir.x, cv.x, air); aiz = fmaf(iz.x, cv.x, aiz); ain = fmaf(in.x, cv.x, ain);
    ahr = fmaf(hr.x, hv.x, ahr); ahz = fmaf(hz.x, hv.x, ahz); ahn = fmaf(hn.x, hv.x, ahn);
    air = fmaf(ir.y, cv.y, air); aiz = fmaf(iz.y, cv.y, aiz); ain = fmaf(in.y, cv.y, ain);
    ahr = fmaf(hr.y, hv.y, ahr); ahz = fmaf(hz.y, hv.y, ahz); ahn = fmaf(hn.y, hv.y, ahn);
    air = fmaf(ir.z, cv.z, air); aiz = fmaf(iz.z, cv.z, aiz); ain = fmaf(in.z, cv.z, ain);
    ahr = fmaf(hr.z, hv.z, ahr); ahz = fmaf(hz.z, hv.z, ahz); ahn = fmaf(hn.z, hv.z, ahn);
    air = fmaf(ir.w, cv.w, air); aiz = fmaf(iz.w, cv.w, aiz); ain = fmaf(in.w, cv.w, ain);
    ahr = fmaf(hr.w, hv.w, ahr); ahz = fmaf(hz.w, hv.w, ahz); ahn = fmaf(hn.w, hv.w, ahn);
  }
  red[(slot * 6 + 0) * 32 + b] = air;
  red[(slot * 6 + 1) * 32 + b] = aiz;
  red[(slot * 6 + 2) * 32 + b] = ain;
  red[(slot * 6 + 3) * 32 + b] = ahr;
  red[(slot * 6 + 4) * 32 + b] = ahz;
  red[(slot * 6 + 5) * 32 + b] = ahn;
  __syncthreads();

  if (tid < 64) {
    int bb = tid & 31, uu = tid >> 5;
    int jj = jc * 2 + uu;
    float sir = 0.f, siz = 0.f, sin_ = 0.f, shr = 0.f, shz = 0.f, shn = 0.f;
    #pragma unroll
    for (int s2 = uu * 4; s2 < uu * 4 + 4; s2++) {
      sir  += red[(s2 * 6 + 0) * 32 + bb];
      siz  += red[(s2 * 6 + 1) * 32 + bb];
      sin_ += red[(s2 * 6 + 2) * 32 + bb];
      shr  += red[(s2 * 6 + 3) * 32 + bb];
      shz  += red[(s2 * 6 + 4) * 32 + bb];
      shn  += red[(s2 * 6 + 5) * 32 + bb];
    }
    int col = t * B_ + bb;
    float ir  = gi_pe[(size_t)jj * (L_ * B_) + col]            + upbT[jj * B_ + bb]            + sir;
    float iz  = gi_pe[(size_t)(H_ + jj) * (L_ * B_) + col]     + upbT[(H_ + jj) * B_ + bb]     + siz;
    float in_ = gi_pe[(size_t)(2 * H_ + jj) * (L_ * B_) + col] + upbT[(2 * H_ + jj) * B_ + bb] + sin_;
    float r = fsig(ir + shr + bhh[jj]);
    float z = fsig(iz + shz + bhh[H_ + jj]);
    float n = ftanh(in_ + r * (shn + bhh[2 * H_ + jj]));
    float hp = hB_in[bb * H_ + jj];
    hB_out[bb * H_ + jj] = (1.f - z) * n + z * hp;
  }
}

// qW[b][i] = h . query_W[i], k-split. grid 256 (2 i each).
__global__ __launch_bounds__(256) void k_qw2(const float* __restrict__ hB,
    const float* __restrict__ queryW, float* __restrict__ qOut)
{
  __shared__ float red[8 * 32];
  const int ic = blockIdx.x;
  const int tid = threadIdx.x;
  const int b = tid & 31, slot = tid >> 5, u = slot >> 2, ks = slot & 3;
  const int i = ic * 2 + u;
  const float4* w4 = (const float4*)(queryW + (size_t)i * H_ + ks * 128);
  const float4* h4 = (const float4*)(hB + b * H_ + ks * 128);
  float a = 0.f;
  #pragma unroll 4
  for (int k4 = 0; k4 < 32; k4++) {
    float4 wv = w4[k4];
    float4 hv = h4[k4];
    a = fmaf(wv.x, hv.x, a);
    a = fmaf(wv.y, hv.y, a);
    a = fmaf(wv.z, hv.z, a);
    a = fmaf(wv.w, hv.w, a);
  }
  red[slot * 32 + b] = a;
  __syncthreads();
  if (tid < 64) {
    int bb = tid & 31, uu = tid >> 5;
    int ii = ic * 2 + uu;
    float s = red[(uu * 4 + 0) * 32 + bb] + red[(uu * 4 + 1) * 32 + bb]
            + red[(uu * 4 + 2) * 32 + bb] + red[(uu * 4 + 3) * 32 + bb];
    qOut[bb * H_ + ii] = s;
  }
}

// scores: one wave per (b,s). grid (32, 100), block 256 (4 waves).
__global__ __launch_bounds__(256) void k_scores2(const float* __restrict__ pk,
    const float* __restrict__ q, const float* __restrict__ energy,
    const int* __restrict__ mask, float* __restrict__ scores)
{
  int b = blockIdx.x;
  int s = blockIdx.y * 4 + (threadIdx.x >> 6);
  int ln = threadIdx.x & 63;
  const float4* q4 = (const float4*)(q + b * H_) + ln * 2;
  float4 q0 = q4[0], q1 = q4[1];
  const float4* e4 = (const float4*)energy + ln * 2;
  float4 e0 = e4[0], e1 = e4[1];
  const float4* p4 = (const float4*)(pk + ((size_t)b * S_ + s) * H_) + ln * 2;
  float4 p0 = p4[0], p1 = p4[1];
  float acc = 0.f;
  acc = fmaf(e0.x, ftanh(q0.x + p0.x), acc);
  acc = fmaf(e0.y, ftanh(q0.y + p0.y), acc);
  acc = fmaf(e0.z, ftanh(q0.z + p0.z), acc);
  acc = fmaf(e0.w, ftanh(q0.w + p0.w), acc);
  acc = fmaf(e1.x, ftanh(q1.x + p1.x), acc);
  acc = fmaf(e1.y, ftanh(q1.y + p1.y), acc);
  acc = fmaf(e1.z, ftanh(q1.z + p1.z), acc);
  acc = fmaf(e1.w, ftanh(q1.w + p1.w), acc);
  #pragma unroll
  for (int off = 32; off > 0; off >>= 1) acc += __shfl_xor(acc, off, 64);
  if (ln == 0)
    scores[b * S_ + s] = (mask[b * S_ + s] == 0) ? -__builtin_inff() : acc;
}

// ---------------------------------------------------------------------------
// Fused softmax + context. grid (32 b, 16 dc), block 256.
// Each block recomputes the (cheap) softmax into LDS; dc==0 also writes the
// global alphas row (needed by k_scatter). Then s-split context for 64 d.
// ctx output layout ctxB[b][d].
// ---------------------------------------------------------------------------
__global__ __launch_bounds__(256) void k_smctx(const float* __restrict__ hs_f,
    const float* __restrict__ hs_b, const float* __restrict__ scores,
    float* __restrict__ alphas, float* __restrict__ ctxB, int t)
{
  __shared__ float al[S_];
  __shared__ float red8[8];
  __shared__ float cred[4][64];
  int b = blockIdx.x, dc = blockIdx.y;
  int tid = threadIdx.x;
  const float* sr = scores + b * S_;
  float x1 = sr[tid];
  float x2 = (tid < S_ - 256) ? sr[256 + tid] : -__builtin_inff();
  float m = fmaxf(x1, x2);
  #pragma unroll
  for (int off = 32; off > 0; off >>= 1) m = fmaxf(m, __shfl_xor(m, off, 64));
  if ((tid & 63) == 0) red8[tid >> 6] = m;
  __syncthreads();
  m = fmaxf(fmaxf(red8[0], red8[1]), fmaxf(red8[2], red8[3]));
  __syncthreads();
  float ex1 = __expf(x1 - m);
  float ex2 = (tid < S_ - 256) ? __expf(x2 - m) : 0.f;
  float s = ex1 + ex2;
  #pragma unroll
  for (int off = 32; off > 0; off >>= 1) s += __shfl_xor(s, off, 64);
  if ((tid & 63) == 0) red8[tid >> 6] = s;
  __syncthreads();
  s = red8[0] + red8[1] + red8[2] + red8[3];
  float inv = 1.f / s;
  al[tid] = ex1 * inv;
  if (tid < S_ - 256) al[256 + tid] = ex2 * inv;
  if (dc == 0) {
    float* alg = alphas + ((size_t)b * L_ + t) * S_;
    alg[tid] = ex1 * inv;
    if (tid < S_ - 256) alg[256 + tid] = ex2 * inv;
  }
  __syncthreads();

  // context: 64 d per block, 4-way s-split
  int dl = tid & 63, sp = tid >> 6;
  int d = dc * 64 + dl;
  const float* srcp = (d < H_) ? (hs_f + (size_t)b * H_ + d)
                               : (hs_b + (size_t)b * H_ + (d - H_));
  float acc = 0.f;
  #pragma unroll 4
  for (int ss = sp * 100; ss < sp * 100 + 100; ss++)
    acc = fmaf(al[ss], srcp[(size_t)ss * (B_ * H_)], acc);
  cred[sp][dl] = acc;
  __syncthreads();
  if (sp == 0)
    ctxB[b * (2 * H_) + d] = cred[0][dl] + cred[1][dl] + cred[2][dl] + cred[3][dl];
}

// ---------------------------------------------------------------------------
// ch = tanh([q, ctx] @ ch_W.T), k-split (blocks 0..255) + gp (block 256).
// ---------------------------------------------------------------------------
__global__ __launch_bounds__(256) void k_chgp2(const float* __restrict__ hB,
    const float* __restrict__ ctxB, const float* __restrict__ chW,
    float* __restrict__ cB_out, u16* __restrict__ ch_hi, u16* __restrict__ ch_lo,
    const float* __restrict__ genpW, const float* __restrict__ genpB,
    const u16* __restrict__ pe_hi, const u16* __restrict__ pe_lo,
    float* __restrict__ gp_all, int t)
{
  if (blockIdx.x < 256) {
    __shared__ float red[8 * 32];
    const int ic = blockIdx.x;
    const int tid = threadIdx.x;
    const int b = tid & 31, slot = tid >> 5, u = slot >> 2, ks = slot & 3;
    const int i = ic * 2 + u;
    const float4* wh4 = (const float4*)(chW + (size_t)i * (3 * H_) + ks * 128);
    const float4* wc4 = (const float4*)(chW + (size_t)i * (3 * H_) + H_ + ks * 256);
    const float4* h4 = (const float4*)(hB + b * H_ + ks * 128);
    const float4* c4 = (const float4*)(ctxB + b * (2 * H_) + ks * 256);
    float a = 0.f;
    #pragma unroll 4
    for (int k4 = 0; k4 < 32; k4++) {
      float4 wv = wh4[k4];
      float4 hv = h4[k4];
      a = fmaf(wv.x, hv.x, a); a = fmaf(wv.y, hv.y, a);
      a = fmaf(wv.z, hv.z, a); a = fmaf(wv.w, hv.w, a);
    }
    #pragma unroll 4
    for (int k4 = 0; k4 < 64; k4++) {
      float4 wv = wc4[k4];
      float4 cv = c4[k4];
      a = fmaf(wv.x, cv.x, a); a = fmaf(wv.y, cv.y, a);
      a = fmaf(wv.z, cv.z, a); a = fmaf(wv.w, cv.w, a);
    }
    red[slot * 32 + b] = a;
    __syncthreads();
    if (tid < 64) {
      int bb = tid & 31, uu = tid >> 5;
      int ii = ic * 2 + uu;
      float sum = red[(uu * 4 + 0) * 32 + bb] + red[(uu * 4 + 1) * 32 + bb]
                + red[(uu * 4 + 2) * 32 + bb] + red[(uu * 4 + 3) * 32 + bb];
      float c = ftanh(sum);
      cB_out[bb * H_ + ii] = c;
      u16 hi = f2bf(c);
      ch_hi[((size_t)bb * L_ + t) * H_ + ii] = hi;
      ch_lo[((size_t)bb * L_ + t) * H_ + ii] = f2bf(c - bf2f(hi));
    }
  } else {
    // gp = sigmoid([context(1024), q(512), pe(256)] . genp_W + genp_b)
    __shared__ float sred[256];
    int b = threadIdx.x & 31, seg = threadIdx.x >> 5;
    float a = 0.f;
    for (int ii = 0; ii < 224; ii++) {
      int idx = seg * 224 + ii;
      float v;
      if (idx < 2 * H_)            v = ctxB[b * (2 * H_) + idx];
      else if (idx < 3 * H_)       v = hB[b * H_ + (idx - 2 * H_)];
      else {
        size_t pidx = ((size_t)t * B_ + b) * E_ + (idx - 3 * H_);
        v = bf2f(pe_hi[pidx]) + bf2f(pe_lo[pidx]);
      }
      a = fmaf(genpW[idx], v, a);
    }
    sred[threadIdx.x] = a;
    __syncthreads();
    if (threadIdx.x < 32) {
      float s = 0.f;
      #pragma unroll
      for (int sg = 0; sg < 8; sg++) s += sred[sg * 32 + threadIdx.x];
      gp_all[threadIdx.x * L_ + t] = fsig(s + genpB[0]);
    }
  }
}

// per-row (1600 rows) max & sumexp over V=50000 logits (in d_out)
__global__ __launch_bounds__(256) void k_rowstats(const float* __restrict__ logits,
    float* __restrict__ stats)
{
  int row = blockIdx.x;
  int tid = threadIdx.x;
  __shared__ float red[8];
  const float* p = logits + (size_t)row * V_;
  float m = -__builtin_inff();
  for (int c = tid; c < V_; c += 256) m = fmaxf(m, p[c]);
  #pragma unroll
  for (int off = 32; off > 0; off >>= 1) m = fmaxf(m, __shfl_xor(m, off, 64));
  if ((tid & 63) == 0) red[tid >> 6] = m;
  __syncthreads();
  m = fmaxf(fmaxf(red[0], red[1]), fmaxf(red[2], red[3]));
  __syncthreads();
  float s = 0.f;
  for (int c = tid; c < V_; c += 256) s += __expf(p[c] - m);
  #pragma unroll
  for (int off = 32; off > 0; off >>= 1) s += __shfl_xor(s, off, 64);
  if ((tid & 63) == 0) red[tid >> 6] = s;
  __syncthreads();
  if (tid == 0) {
    stats[row * 2]     = m;
    stats[row * 2 + 1] = red[0] + red[1] + red[2] + red[3];
  }
}

// out = gp * softmax(logits) in-place; grid (49, 1600), float4 per thread
__global__ __launch_bounds__(256) void k_mix(float* __restrict__ out,
    const float* __restrict__ stats, const float* __restrict__ gp_all)
{
  int row = blockIdx.y;
  int c4 = blockIdx.x * 256 + threadIdx.x;
  if (c4 >= V_ / 4) return;
  float m = stats[row * 2], s = stats[row * 2 + 1];
  float inv = gp_all[row] / s;
  float4* p = (float4*)(out + (size_t)row * V_) + c4;
  float4 v = *p;
  v.x = __expf(v.x - m) * inv;
  v.y = __expf(v.y - m) * inv;
  v.z = __expf(v.z - m) * inv;
  v.w = __expf(v.w - m) * inv;
  *p = v;
}

// copy mechanism: out[b,l,src[b,s]] += (1-gp)*alpha
__global__ __launch_bounds__(256) void k_scatter(float* __restrict__ out,
    const float* __restrict__ alphas, const float* __restrict__ gp_all,
    const int* __restrict__ src)
{
  int gid = blockIdx.x * 256 + threadIdx.x;
  if (gid >= B_ * L_ * S_) return;
  int s = gid % S_;
  int bl = gid / S_;     // b*50+l
  int b = bl / L_;
  float a = alphas[(size_t)bl * S_ + s];
  float g = gp_all[bl];
  int v = src[b * S_ + s];
  atomicAdd(out + (size_t)bl * V_ + v, (1.f - g) * a);
}

// ---------------------------------------------------------------------------
// Host launcher
// ---------------------------------------------------------------------------
extern "C" void kernel_launch(void* const* d_in, const int* in_sizes, int n_in,
                              void* d_out, int out_size, void* d_ws, size_t ws_size,
                              hipStream_t stream) {
  const int*   src     = (const int*)d_in[0];
  const int*   trg     = (const int*)d_in[1];
  const int*   user    = (const int*)d_in[2];
  const int*   product = (const int*)d_in[3];
  const int*   mask    = (const int*)d_in[4];
  const float* embW    = (const float*)d_in[6];
  const float* userW   = (const float*)d_in[7];
  const float* prodW   = (const float*)d_in[8];
  const float* eWihF   = (const float*)d_in[9];
  const float* eWhhF   = (const float*)d_in[10];
  const float* eBihF   = (const float*)d_in[11];
  const float* eBhhF   = (const float*)d_in[12];
  const float* eWihB   = (const float*)d_in[13];
  const float* eWhhB   = (const float*)d_in[14];
  const float* eBihB   = (const float*)d_in[15];
  const float* eBhhB   = (const float*)d_in[16];
  const float* initW   = (const float*)d_in[17];
  const float* initB   = (const float*)d_in[18];
  const float* keyW    = (const float*)d_in[19];
  const float* queryW  = (const float*)d_in[20];
  const float* energyW = (const float*)d_in[21];
  const float* decWih  = (const float*)d_in[22];
  const float* decWhh  = (const float*)d_in[23];
  const float* decBih  = (const float*)d_in[24];
  const float* decBhh  = (const float*)d_in[25];
  const float* chW     = (const float*)d_in[26];
  const float* genpW   = (const float*)d_in[27];
  const float* genpB   = (const float*)d_in[28];
  const float* genW    = (const float*)d_in[29];
  float* out = (float*)d_out;

  char* ws = (char*)d_ws;
  size_t off = 0;
  auto alloc = [&](size_t bytes) -> void* {
    void* p = ws + off;
    off = (off + bytes + 255) & ~(size_t)255;
    return p;
  };

  // Persistent buffers
  u16* x_hi    = (u16*)alloc((size_t)S_ * B_ * E_ * 2);
  u16* x_lo    = (u16*)alloc((size_t)S_ * B_ * E_ * 2);
  u16* wihF_hi = (u16*)alloc((size_t)G3 * E_ * 2);
  u16* wihF_lo = (u16*)alloc((size_t)G3 * E_ * 2);
  u16* wihB_hi = (u16*)alloc((size_t)G3 * E_ * 2);
  u16* wihB_lo = (u16*)alloc((size_t)G3 * E_ * 2);
  u16* wpe_hi  = (u16*)alloc((size_t)G3 * E_ * 2);
  u16* wpe_lo  = (u16*)alloc((size_t)G3 * E_ * 2);
  u16* key_hi  = (u16*)alloc((size_t)H_ * 2 * H_ * 2);
  u16* key_lo  = (u16*)alloc((size_t)H_ * 2 * H_ * 2);
  u16* pe_hi   = (u16*)alloc((size_t)L_ * B_ * E_ * 2);
  u16* pe_lo   = (u16*)alloc((size_t)L_ * B_ * E_ * 2);
  float* gi_pe = (float*)alloc((size_t)G3 * L_ * B_ * 4);
  float* hs_f  = (float*)alloc((size_t)S_ * B_ * H_ * 4);
  float* hs_b  = (float*)alloc((size_t)S_ * B_ * H_ * 4);
  float* hBe0  = (float*)alloc(2 * H_ * B_ * 4);
  float* hBe1  = (float*)alloc(2 * H_ * B_ * 4);
  float* upbT  = (float*)alloc((size_t)G3 * B_ * 4);
  float* hD0   = (float*)alloc(H_ * B_ * 4);
  float* hD1   = (float*)alloc(H_ * B_ * 4);
  float* cD0   = (float*)alloc(H_ * B_ * 4);
  float* cD1   = (float*)alloc(H_ * B_ * 4);
  float* qW    = (float*)alloc(B_ * H_ * 4);
  float* scores= (float*)alloc(B_ * S_ * 4);
  float* ctxB  = (float*)alloc(2 * H_ * B_ * 4);
  float* alphas= (float*)alloc((size_t)B_ * L_ * S_ * 4);
  float* gp_all= (float*)alloc(B_ * L_ * 4);
  u16* ch_hi   = (u16*)alloc((size_t)B_ * L_ * H_ * 2);
  u16* ch_lo   = (u16*)alloc((size_t)B_ * L_ * H_ * 2);
  float* stats = (float*)alloc(B_ * L_ * 2 * 4);

  // Aliased region: phase1 {gi_f, gi_b fp32} -> phase2 {genW hi/lo, ehid hi/lo, pk}
  size_t ph1 = 2 * (size_t)G3 * S_ * B_ * 4;                               // 157.3 MB
  size_t ph2 = 2 * (size_t)VPAD * H_ * 2 + 2 * (size_t)B_ * S_ * 2 * H_ * 2
             + (size_t)B_ * S_ * H_ * 4;                                   // 181.1 MB
  char* region = (char*)alloc(ph1 > ph2 ? ph1 : ph2);
  float* gi_f = (float*)region;
  float* gi_b = gi_f + (size_t)G3 * S_ * B_;
  u16* genw_hi = (u16*)region;
  u16* genw_lo = genw_hi + (size_t)VPAD * H_;
  u16* ehid_hi = genw_lo + (size_t)VPAD * H_;
  u16* ehid_lo = ehid_hi + (size_t)B_ * S_ * 2 * H_;
  float* pk    = (float*)(ehid_lo + (size_t)B_ * S_ * 2 * H_);
  (void)ws_size; (void)in_sizes; (void)n_in; (void)out_size;

  // ---- setup / conversions ----
  hipMemsetAsync(hBe0, 0, 2 * H_ * B_ * 4, stream);

  k_embed<<<S_ * B_, 256, 0, stream>>>(src, embW, x_hi, x_lo);
  k_pe<<<L_ * B_, 256, 0, stream>>>(trg, embW, pe_hi, pe_lo);

  {
    long tot = (long)G3 * E_;
    k_conv<<<(tot + 255) / 256, 256, 0, stream>>>(eWihF, wihF_hi, wihF_lo, G3, E_, E_, tot);
    k_conv<<<(tot + 255) / 256, 256, 0, stream>>>(eWihB, wihB_hi, wihB_lo, G3, E_, E_, tot);
    k_conv<<<(tot + 255) / 256, 256, 0, stream>>>(decWih, wpe_hi, wpe_lo, G3, E_, E_ + H_ + 2 * A_, tot);
    long tk = (long)H_ * 2 * H_;
    k_conv<<<(tk + 255) / 256, 256, 0, stream>>>(keyW, key_hi, key_lo, H_, 2 * H_, 2 * H_, tk);
  }
  k_upbias<<<(G3 * B_) / 256, 256, 0, stream>>>(user, product, userW, prodW, decWih, decBih, upbT);

  // gi = Wih @ x^T : (1536, 12800) f32
  k_gemm3<<<dim3((S_ * B_) / 64, G3 / 64), 256, 0, stream>>>(wihF_hi, wihF_lo, x_hi, x_lo, gi_f, G3, S_ * B_, E_, S_ * B_, S_ * B_);
  k_gemm3<<<dim3((S_ * B_) / 64, G3 / 64), 256, 0, stream>>>(wihB_hi, wihB_lo, x_hi, x_lo, gi_b, G3, S_ * B_, E_, S_ * B_, S_ * B_);

  // gi_pe = Wpe @ pe^T : (1536, 1600) f32
  k_gemm3<<<dim3((L_ * B_) / 64, G3 / 64), 256, 0, stream>>>(wpe_hi, wpe_lo, pe_hi, pe_lo, gi_pe, G3, L_ * B_, E_, L_ * B_, L_ * B_);

  // ---- encoder recurrence (400 steps, fwd+bwd in one launch, k-split) ----
  for (int t = 0; t < S_; t++) {
    float* hin  = (t & 1) ? hBe1 : hBe0;
    float* hout = (t & 1) ? hBe0 : hBe1;
    k_enc_step2<<<512, 256, 0, stream>>>(gi_f, gi_b, eWhhF, eWhhB,
        eBihF, eBhhF, eBihB, eBhhB, hin, hout, hs_f, hs_b, t);
  }

  // ---- phase 2 of aliased region: gi_f/gi_b dead from here on ----
  {
    long tg = (long)VPAD * H_;
    k_conv<<<(tg + 255) / 256, 256, 0, stream>>>(genW, genw_hi, genw_lo, V_, H_, H_, tg);
  }
  k_pack<<<B_ * S_, 256, 0, stream>>>(hs_f, hs_b, ehid_hi, ehid_lo);
  // proj_key = ehid @ key_W^T : (12800, 512) f32
  k_gemm3<<<dim3(H_ / 64, (B_ * S_) / 64), 256, 0, stream>>>(ehid_hi, ehid_lo, key_hi, key_lo, pk, B_ * S_, H_, 2 * H_, H_, H_);

  k_dec_init<<<64, 256, 0, stream>>>(hs_f, hs_b, initW, initB, hD0, cD0);

  // ---- decoder recurrence (50 steps x 5 launches) ----
  for (int t = 0; t < L_; t++) {
    float* hin  = (t & 1) ? hD1 : hD0;
    float* hout = (t & 1) ? hD0 : hD1;
    float* cin  = (t & 1) ? cD1 : cD0;
    float* cout = (t & 1) ? cD0 : cD1;
    k_dec_gru2<<<256, 256, 0, stream>>>(gi_pe, upbT, decWih, decWhh, decBhh, hin, cin, hout, t);
    k_qw2<<<256, 256, 0, stream>>>(hout, queryW, qW);
    k_scores2<<<dim3(B_, 100), 256, 0, stream>>>(pk, qW, energyW, mask, scores);
    k_smctx<<<dim3(B_, 16), 256, 0, stream>>>(hs_f, hs_b, scores, alphas, ctxB, t);
    k_chgp2<<<257, 256, 0, stream>>>(hout, ctxB, chW, cout, ch_hi, ch_lo,
        genpW, genpB, pe_hi, pe_lo, gp_all, t);
  }

  // ---- output: gen logits -> softmax mix -> copy scatter ----
  k_gemm3<<<dim3(VPAD / 64, (B_ * L_) / 64), 256, 0, stream>>>(ch_hi, ch_lo, genw_hi, genw_lo, out, B_ * L_, VPAD, H_, V_, V_);
  k_rowstats<<<B_ * L_, 256, 0, stream>>>(out, stats);
  k_mix<<<dim3((V_ / 4 + 255) / 256, B_ * L_), 256, 0, stream>>>(out, stats, gp_all);
  k_scatter<<<(B_ * L_ * S_ + 255) / 256, 256, 0, stream>>>(out, alphas, gp_all, src);
}